// Round 7
// baseline (186.503 us; speedup 1.0000x reference)
//
#include <hip/hip_runtime.h>
#include <math.h>

#define HW 512
#define NIMG 24              // 8*3 images per tensor
#define NB 362               // radial bins
#define PLANE (HW*HW)
#define NC 257               // stored spectral columns (0..256), Hermitian half
#define CP (NC*HW)           // 131584 floats per component per image
#define NG 65                // col-groups per image (4 cols each, last ragged)
#define NPB (NIMG*NG)        // 1560 partial-bin blocks

// ws layout (float units):
#define OFF_PM  0                          // [NPB*NB] partial mag sums
#define OFF_PD  (NPB*NB)                   // [NPB*NB] partial d sums
#define OFF_CNT (2*NPB*NB)                 // [NB] int counts
#define OFF_PR  1129808                    // P real, col-major [img][col][row]
#define OFF_PIm (OFF_PR + NIMG*CP)         // P imag
#define OFF_TR  (OFF_PR + 2*NIMG*CP)       // T real
#define OFF_TI  (OFF_PR + 3*NIMG*CP)       // T imag

// Exact bin for ODD integer u,v (as floats): m2 = u^2+v^2 == 2 mod 8 is never
// a perfect even square, boundary gap >= 1/(4k) ~ 6.9e-4 >> 1ulp sqrt err.
__device__ __forceinline__ int rbin_odd(float u, float v) {
    return (int)(sqrtf(fmaf(u, u, v*v)) * 0.5f);
}

__device__ __forceinline__ void cmul(float& xr, float& xi, float wr, float wi) {
    float r = xr*wr - xi*wi;
    xi = xr*wi + xi*wr;
    xr = r;
}

// 8-point DFT in registers, natural order (validated R2-R6).
__device__ __forceinline__ void dft8(float ar[8], float ai[8]) {
    const float C = 0.70710678118654752440f;
    float t0r=ar[0]+ar[4], t0i=ai[0]+ai[4];
    float t1r=ar[0]-ar[4], t1i=ai[0]-ai[4];
    float t2r=ar[2]+ar[6], t2i=ai[2]+ai[6];
    float t3r=ar[2]-ar[6], t3i=ai[2]-ai[6];
    float E0r=t0r+t2r, E0i=t0i+t2i;
    float E2r=t0r-t2r, E2i=t0i-t2i;
    float E1r=t1r+t3i, E1i=t1i-t3r;
    float E3r=t1r-t3i, E3i=t1i+t3r;
    float u0r=ar[1]+ar[5], u0i=ai[1]+ai[5];
    float u1r=ar[1]-ar[5], u1i=ai[1]-ai[5];
    float u2r=ar[3]+ar[7], u2i=ai[3]+ai[7];
    float u3r=ar[3]-ar[7], u3i=ai[3]-ai[7];
    float O0r=u0r+u2r, O0i=u0i+u2i;
    float O2r=u0r-u2r, O2i=u0i-u2i;
    float O1r=u1r+u3i, O1i=u1i-u3r;
    float O3r=u1r-u3i, O3i=u1i+u3r;
    float W1r = C*(O1r+O1i), W1i = C*(O1i-O1r);
    float W2r = O2i,         W2i = -O2r;
    float W3r = C*(O3i-O3r), W3i = -C*(O3r+O3i);
    ar[0]=E0r+O0r; ai[0]=E0i+O0i;
    ar[4]=E0r-O0r; ai[4]=E0i-O0i;
    ar[1]=E1r+W1r; ai[1]=E1i+W1i;
    ar[5]=E1r-W1r; ai[5]=E1i-W1i;
    ar[2]=E2r+W2r; ai[2]=E2i+W2i;
    ar[6]=E2r-W2r; ai[6]=E2i-W2i;
    ar[3]=E3r+W3r; ai[3]=E3i+W3i;
    ar[7]=E3r-W3r; ai[7]=E3i-W3i;
}

__device__ __forceinline__ void twiddle7(float ar[8], float ai[8], float wr, float wi) {
    float pr = wr, pi = wi;
    cmul(ar[1], ai[1], pr, pi);
    #pragma unroll
    for (int k = 2; k < 8; ++k) {
        float nr = pr*wr - pi*wi;
        pi = pr*wi + pi*wr;
        pr = nr;
        cmul(ar[k], ai[k], pr, pi);
    }
}

// TWO interleaved 512-pt FFTs (independent inputs A,B) through ONE per-wave
// scratch (Lr/Li 544 floats each). Correct without barriers: a wave's LDS ops
// execute in issue order, and the compiler must preserve write->read order
// under may-alias. Sharing lets the scheduler fill A's LDS latency with B's
// arithmetic, and the two FFTs share twiddle computation.
// In:  ar[j] = x[64*j + lane];  Out: ar[d] = X[(lane>>3) + 8*(lane&7) + 64*d]
__device__ __forceinline__ void fft512x2(float Ar[8], float Ai[8],
                                         float Br[8], float Bi[8],
                                         float* Lr, float* Li, int lane) {
    float s1, c1, s2, c2;
    int k1 = lane >> 3, b = lane & 7;
    __sincosf((float)lane * (-6.28318530717958647692f/512.0f), &s1, &c1);
    __sincosf((float)b    * (-6.28318530717958647692f/64.0f),  &s2, &c2);
    dft8(Ar, Ai); twiddle7(Ar, Ai, c1, s1);
    dft8(Br, Bi); twiddle7(Br, Bi, c1, s1);
    // ---- exchange 1 (row stride 68: 2-way banks max) ----
    #pragma unroll
    for (int j = 0; j < 8; ++j) { Lr[j*68+lane] = Ar[j]; Li[j*68+lane] = Ai[j]; }
    #pragma unroll
    for (int a = 0; a < 8; ++a) { Ar[a] = Lr[k1*68+8*a+b]; Ai[a] = Li[k1*68+8*a+b]; }
    #pragma unroll
    for (int j = 0; j < 8; ++j) { Lr[j*68+lane] = Br[j]; Li[j*68+lane] = Bi[j]; }
    dft8(Ar, Ai); twiddle7(Ar, Ai, c2, s2);
    #pragma unroll
    for (int a = 0; a < 8; ++a) { Br[a] = Lr[k1*68+8*a+b]; Bi[a] = Li[k1*68+8*a+b]; }
    dft8(Br, Bi); twiddle7(Br, Bi, c2, s2);
    // ---- exchange 2 (swizzled: 2-way banks both directions) ----
    #pragma unroll
    for (int cc = 0; cc < 8; ++cc) {
        int ad = k1*68 + 8*cc + ((b + cc) & 7);
        Lr[ad] = Ar[cc]; Li[ad] = Ai[cc];
    }
    #pragma unroll
    for (int bb = 0; bb < 8; ++bb) {
        int ad = k1*68 + 8*b + ((bb + b) & 7);
        Ar[bb] = Lr[ad]; Ai[bb] = Li[ad];
    }
    #pragma unroll
    for (int cc = 0; cc < 8; ++cc) {
        int ad = k1*68 + 8*cc + ((b + cc) & 7);
        Lr[ad] = Br[cc]; Li[ad] = Bi[cc];
    }
    dft8(Ar, Ai);
    #pragma unroll
    for (int bb = 0; bb < 8; ++bb) {
        int ad = k1*68 + 8*b + ((bb + b) & 7);
        Br[bb] = Lr[ad]; Bi[bb] = Li[ad];
    }
    dft8(Br, Bi);
}

// Bin populations (mirrors np.bincount of r_int).
__global__ __launch_bounds__(256) void k_counts(int* __restrict__ counts) {
    __shared__ int cb[NB];
    int t = threadIdx.x;
    for (int j = t; j < NB; j += 256) cb[j] = 0;
    __syncthreads();
    int base = blockIdx.x * 4096;
    #pragma unroll
    for (int j = 0; j < 16; ++j) {
        int idx = base + t + j*256;
        float u = fabsf(2.0f*(float)(idx >> 9)  - 511.0f);
        float v = fabsf(2.0f*(float)(idx & 511) - 511.0f);
        atomicAdd(&cb[rbin_odd(u, v)], 1);
    }
    __syncthreads();
    for (int j = t; j < NB; j += 256) atomicAdd(&counts[j], cb[j]);
}

// Row stage: pack pred-row (re) + tgt-row (im) into one complex FFT; rows A,B
// interleaved in fft512x2; unpack Hermitian halves; store cols 0..256 of P,T
// spectra col-major. Block = 4 waves x 2 rows = 8 rows. 24*64 blocks.
__global__ __launch_bounds__(256, 6) void k_rowfft(const float* __restrict__ pred,
                                                   const float* __restrict__ tgt,
                                                   float* __restrict__ ws) {
    __shared__ float smem[4672];           // 4x1088 scratch; [257][9] tiles alias
    int t = threadIdx.x, lane = t & 63, w = t >> 6;
    int b = blockIdx.x;
    int img = b >> 6;
    int r0 = (b & 63) << 3;
    int rA = r0 + 2*w;
    const float* pA = pred + (size_t)img*PLANE + (size_t)rA*HW;
    const float* tA = tgt  + (size_t)img*PLANE + (size_t)rA*HW;
    float arA[8], aiA[8], arB[8], aiB[8];
    #pragma unroll
    for (int j = 0; j < 8; ++j) {          // all 32 loads in flight
        arA[j] = pA[64*j + lane];      aiA[j] = tA[64*j + lane];
        arB[j] = pA[HW + 64*j + lane]; aiB[j] = tA[HW + 64*j + lane];
    }
    float* Lr = smem + w*1088;
    float* Li = Lr + 544;
    fft512x2(arA, aiA, arB, aiB, Lr, Li, lane);
    // stash A natural, unpack A pairs
    float PrA[4], PiA[4], TrA[4], TiA[4], P256A=0.f, T256A=0.f;
    float PrB[4], PiB[4], TrB[4], TiB[4], P256B=0.f, T256B=0.f;
    #pragma unroll
    for (int d = 0; d < 8; ++d) {
        int k = (lane>>3) + ((lane&7)<<3) + (d<<6);
        Lr[k] = arA[d]; Li[k] = aiA[d];
    }
    #pragma unroll
    for (int m = 0; m < 4; ++m) {
        int kk = 64*m + lane, j2 = (512 - kk) & 511;
        float z1r = Lr[kk], z1i = Li[kk], z2r = Lr[j2], z2i = Li[j2];
        PrA[m] = 0.5f*(z1r+z2r); PiA[m] = 0.5f*(z1i-z2i);
        TrA[m] = 0.5f*(z1i+z2i); TiA[m] = 0.5f*(z2r-z1r);
    }
    if (lane == 0) { P256A = Lr[256]; T256A = Li[256]; }
    // stash B natural, unpack B pairs (safe after A reads: in-order LDS)
    #pragma unroll
    for (int d = 0; d < 8; ++d) {
        int k = (lane>>3) + ((lane&7)<<3) + (d<<6);
        Lr[k] = arB[d]; Li[k] = aiB[d];
    }
    #pragma unroll
    for (int m = 0; m < 4; ++m) {
        int kk = 64*m + lane, j2 = (512 - kk) & 511;
        float z1r = Lr[kk], z1i = Li[kk], z2r = Lr[j2], z2i = Li[j2];
        PrB[m] = 0.5f*(z1r+z2r); PiB[m] = 0.5f*(z1i-z2i);
        TrB[m] = 0.5f*(z1i+z2i); TiB[m] = 0.5f*(z2r-z1r);
    }
    if (lane == 0) { P256B = Lr[256]; T256B = Li[256]; }

    float* TAt = smem;                     // [257][9]
    float* TBt = smem + 2336;
    // ---- P planes ----
    __syncthreads();
    #pragma unroll
    for (int m = 0; m < 4; ++m) {
        int kk = 64*m + lane;
        TAt[kk*9 + 2*w]   = PrA[m]; TAt[kk*9 + 2*w+1] = PrB[m];
        TBt[kk*9 + 2*w]   = PiA[m]; TBt[kk*9 + 2*w+1] = PiB[m];
    }
    if (lane == 0) {
        TAt[256*9 + 2*w] = P256A; TAt[256*9 + 2*w+1] = P256B;
        TBt[256*9 + 2*w] = 0.f;   TBt[256*9 + 2*w+1] = 0.f;
    }
    __syncthreads();
    for (int idx = t; idx < 2*NC; idx += 256) {
        int comp = (idx >= NC);
        int col = idx - comp*NC;
        const float* Tt = comp ? TBt : TAt;
        float* outP = ws + (size_t)(comp ? OFF_PIm : OFF_PR)
                      + (size_t)img*CP + (size_t)col*HW + r0;
        *(float4*)outP       = make_float4(Tt[col*9],   Tt[col*9+1], Tt[col*9+2], Tt[col*9+3]);
        *(float4*)(outP + 4) = make_float4(Tt[col*9+4], Tt[col*9+5], Tt[col*9+6], Tt[col*9+7]);
    }
    // ---- T planes ----
    __syncthreads();
    #pragma unroll
    for (int m = 0; m < 4; ++m) {
        int kk = 64*m + lane;
        TAt[kk*9 + 2*w]   = TrA[m]; TAt[kk*9 + 2*w+1] = TrB[m];
        TBt[kk*9 + 2*w]   = TiA[m]; TBt[kk*9 + 2*w+1] = TiB[m];
    }
    if (lane == 0) {
        TAt[256*9 + 2*w] = T256A; TAt[256*9 + 2*w+1] = T256B;
        TBt[256*9 + 2*w] = 0.f;   TBt[256*9 + 2*w+1] = 0.f;
    }
    __syncthreads();
    for (int idx = t; idx < 2*NC; idx += 256) {
        int comp = (idx >= NC);
        int col = idx - comp*NC;
        const float* Tt = comp ? TBt : TAt;
        float* outP = ws + (size_t)(comp ? OFF_TI : OFF_TR)
                      + (size_t)img*CP + (size_t)col*HW + r0;
        *(float4*)outP       = make_float4(Tt[col*9],   Tt[col*9+1], Tt[col*9+2], Tt[col*9+3]);
        *(float4*)(outP + 4) = make_float4(Tt[col*9+4], Tt[col*9+5], Tt[col*9+6], Tt[col*9+7]);
    }
}

// Col stage: interleaved P,T column FFTs; per-pixel (mag,d2) stash in scratch;
// bin PAIRS (ky, 511-ky share a bin) for the column and its x-mirror.
__global__ __launch_bounds__(256, 6) void k_colfft(const float* __restrict__ ws,
                                                   float* __restrict__ gPM,
                                                   float* __restrict__ gPD) {
    __shared__ float smem[4352];
    __shared__ float binM[NB], binD[NB];
    int t = threadIdx.x, lane = t & 63, w = t >> 6;
    for (int j = t; j < NB; j += 256) { binM[j] = 0.f; binD[j] = 0.f; }
    __syncthreads();
    int b = blockIdx.x;
    int img = b / NG;
    int g = b - img*NG;
    int c = 4*g + w;
    if (c < NC) {
        float* Lr = smem + w*1088;
        float* Li = Lr + 544;
        float prm[8], pim[8], trm[8], tim[8];
        const float* cPR = ws + OFF_PR  + (size_t)img*CP + (size_t)c*HW;
        const float* cPI = ws + OFF_PIm + (size_t)img*CP + (size_t)c*HW;
        const float* cTR = ws + OFF_TR  + (size_t)img*CP + (size_t)c*HW;
        const float* cTI = ws + OFF_TI  + (size_t)img*CP + (size_t)c*HW;
        #pragma unroll
        for (int j = 0; j < 8; ++j) {      // all 32 loads in flight
            prm[j] = cPR[64*j+lane]; pim[j] = cPI[64*j+lane];
            trm[j] = cTR[64*j+lane]; tim[j] = cTI[64*j+lane];
        }
        fft512x2(prm, pim, trm, tim, Lr, Li, lane);
        // per-pixel mag/d2 into scratch, indexed by true ky (conflict-free)
        #pragma unroll
        for (int d = 0; d < 8; ++d) {
            int ky = (lane>>3) + ((lane&7)<<3) + (d<<6);
            float sp  = prm[d]*prm[d] + pim[d]*pim[d];
            float st_ = trm[d]*trm[d] + tim[d]*tim[d];
            float diff = sp - st_;
            float er = prm[d] + 1e-8f;
            Lr[ky] = 10.0f * __logf(er*er + pim[d]*pim[d]);
            Li[ky] = diff*diff;
        }
        float v1 = (c == 256) ? 511.0f : (float)(2*c + 1);
        bool mir = (c >= 1 && c <= 255);
        float v2 = (float)(2*c - 1);
        #pragma unroll
        for (int p = 0; p < 4; ++p) {
            int ky = lane + 64*p;          // [0,256): pair partner is 511-ky
            float u = (float)(2*ky + 1);
            float sM = Lr[ky] + Lr[511 - ky];
            float sD = Li[ky] + Li[511 - ky];
            int k1 = rbin_odd(u, v1);
            atomicAdd(&binM[k1], sM);
            atomicAdd(&binD[k1], sD);
            if (mir) {                     // mirror col pair-sum: same LDS array
                float s2M = Lr[(512 - ky) & 511] + Lr[ky + 1];
                float s2D = Li[(512 - ky) & 511] + Li[ky + 1];
                int k2 = rbin_odd(u, v2);
                atomicAdd(&binM[k2], s2M);
                atomicAdd(&binD[k2], s2D);
            }
        }
    }
    __syncthreads();
    for (int j = t; j < NB; j += 256) {
        gPM[(size_t)b*NB + j] = binM[j];
        gPD[(size_t)b*NB + j] = binD[j];
    }
}

// Per-image: reduce partials -> bin means -> NaN-propagating min/max ->
// weights -> weighted sum -> atomic into d_out. (Numerics validated R1-R6.)
__global__ __launch_bounds__(512) void k_final(const float* __restrict__ gPM,
                                               const float* __restrict__ gPD,
                                               const int* __restrict__ counts,
                                               float* __restrict__ out) {
    __shared__ float meanb[NB];
    __shared__ float dsum[NB];
    __shared__ float rmin[512], rmax[512];
    __shared__ double sred[512];
    int t = threadIdx.x, img = blockIdx.x;
    for (int j = t; j < NB; j += 512) {
        float sm = 0.f, sd = 0.f;
        for (int g = 0; g < NG; ++g) {
            sm += gPM[(size_t)(img*NG + g)*NB + j];
            sd += gPD[(size_t)(img*NG + g)*NB + j];
        }
        meanb[j] = sm / (float)counts[j];
        dsum[j] = sd;
    }
    __syncthreads();
    float vmin = INFINITY, vmax = -INFINITY;
    if (t >= 1 && t <= 360) { vmin = meanb[t]; vmax = meanb[t]; }
    rmin[t] = vmin; rmax[t] = vmax;
    __syncthreads();
    for (int s = 256; s > 0; s >>= 1) {
        if (t < s) {
            float a = rmin[t], bb = rmin[t+s];
            rmin[t] = (a != a || bb != bb) ? __int_as_float(0x7fc00000) : fminf(a, bb);
            a = rmax[t]; bb = rmax[t+s];
            rmax[t] = (a != a || bb != bb) ? __int_as_float(0x7fc00000) : fmaxf(a, bb);
        }
        __syncthreads();
    }
    float pmin = rmin[0], pmax = rmax[0];
    double part = 0.0;
    for (int k = t; k < NB; k += 512) {
        float wgt;
        if (k == NB - 1) {
            wgt = 1.0f;
        } else {
            int idx = (k == 0) ? 1 : k;
            float e = (meanb[idx] - pmin) / (pmax - pmin);
            float wv = 1.0f - e;
            if (wv != wv) wv = 0.0f;
            wv = fminf(fmaxf(wv, 0.0f), 1.0f);
            wgt = wv;
        }
        part += (double)wgt * (double)dsum[k];
    }
    sred[t] = part;
    __syncthreads();
    for (int s = 256; s > 0; s >>= 1) {
        if (t < s) sred[t] += sred[t+s];
        __syncthreads();
    }
    if (t == 0) atomicAdd(out, (float)(sred[0] / 6291456.0));
}

extern "C" void kernel_launch(void* const* d_in, const int* in_sizes, int n_in,
                              void* d_out, int out_size, void* d_ws, size_t ws_size,
                              hipStream_t stream) {
    const float* pred = (const float*)d_in[0];
    const float* tgt  = (const float*)d_in[1];
    float* ws = (float*)d_ws;
    hipMemsetAsync((char*)d_ws + (size_t)OFF_CNT*4, 0, NB*4, stream);
    hipMemsetAsync(d_out, 0, sizeof(float), stream);
    k_counts<<<64, 256, 0, stream>>>((int*)(ws + OFF_CNT));
    k_rowfft<<<NIMG*64, 256, 0, stream>>>(pred, tgt, ws);
    k_colfft<<<NPB, 256, 0, stream>>>(ws, ws + OFF_PM, ws + OFF_PD);
    k_final<<<NIMG, 512, 0, stream>>>(ws + OFF_PM, ws + OFF_PD,
                                      (const int*)(ws + OFF_CNT), (float*)d_out);
}

// Round 10
// 168.086 us; speedup vs baseline: 1.1096x; 1.1096x over previous
//
#include <hip/hip_runtime.h>
#include <math.h>

#define HW 512
#define NIMG 24              // 8*3 images per tensor
#define NB 362               // radial bins
#define PLANE (HW*HW)
#define NC 257               // spectral columns kept (0..256), Hermitian half
#define NG 65                // col-groups per image (4 cols each; cg64 ragged)
#define NPB (NIMG*NG)        // 1560 partial-bin blocks
#define CP2 133120           // floats per component per image: 65 cg * 512 * 4

// ws layout (float units):
#define OFF_PM  0                          // [NPB*NB] partial mag sums
#define OFF_PD  (NPB*NB)                   // [NPB*NB] partial d sums
#define OFF_PR  (2*NPB*NB)                 // P real, [img][cg][row][4]
#define OFF_PIm (OFF_PR + NIMG*CP2)        // P imag
#define OFF_TR  (OFF_PR + 2*NIMG*CP2)      // T real
#define OFF_TI  (OFF_PR + 3*NIMG*CP2)      // T imag
// total ~55.6 MiB

// Exact bin for ODD integer u,v (as floats): m2 = u^2+v^2 == 2 mod 8 is never
// a perfect even square, boundary gap >= 1/(4k) ~ 6.9e-4 >> 1ulp sqrt err.
__device__ __forceinline__ int rbin_odd(float u, float v) {
    return (int)(sqrtf(fmaf(u, u, v*v)) * 0.5f);
}

__device__ __forceinline__ void cmul(float& xr, float& xi, float wr, float wi) {
    float r = xr*wr - xi*wi;
    xi = xr*wi + xi*wr;
    xr = r;
}

// 8-point DFT in registers, natural order (validated R2-R7).
__device__ __forceinline__ void dft8(float ar[8], float ai[8]) {
    const float C = 0.70710678118654752440f;
    float t0r=ar[0]+ar[4], t0i=ai[0]+ai[4];
    float t1r=ar[0]-ar[4], t1i=ai[0]-ai[4];
    float t2r=ar[2]+ar[6], t2i=ai[2]+ai[6];
    float t3r=ar[2]-ar[6], t3i=ai[2]-ai[6];
    float E0r=t0r+t2r, E0i=t0i+t2i;
    float E2r=t0r-t2r, E2i=t0i-t2i;
    float E1r=t1r+t3i, E1i=t1i-t3r;
    float E3r=t1r-t3i, E3i=t1i+t3r;
    float u0r=ar[1]+ar[5], u0i=ai[1]+ai[5];
    float u1r=ar[1]-ar[5], u1i=ai[1]-ai[5];
    float u2r=ar[3]+ar[7], u2i=ai[3]+ai[7];
    float u3r=ar[3]-ar[7], u3i=ai[3]-ai[7];
    float O0r=u0r+u2r, O0i=u0i+u2i;
    float O2r=u0r-u2r, O2i=u0i-u2i;
    float O1r=u1r+u3i, O1i=u1i-u3r;
    float O3r=u1r-u3i, O3i=u1i+u3r;
    float W1r = C*(O1r+O1i), W1i = C*(O1i-O1r);
    float W2r = O2i,         W2i = -O2r;
    float W3r = C*(O3i-O3r), W3i = -C*(O3r+O3i);
    ar[0]=E0r+O0r; ai[0]=E0i+O0i;
    ar[4]=E0r-O0r; ai[4]=E0i-O0i;
    ar[1]=E1r+W1r; ai[1]=E1i+W1i;
    ar[5]=E1r-W1r; ai[5]=E1i-W1i;
    ar[2]=E2r+W2r; ai[2]=E2i+W2i;
    ar[6]=E2r-W2r; ai[6]=E2i-W2i;
    ar[3]=E3r+W3r; ai[3]=E3i+W3i;
    ar[7]=E3r-W3r; ai[7]=E3i-W3i;
}

__device__ __forceinline__ void twiddle7(float ar[8], float ai[8], float wr, float wi) {
    float pr = wr, pi = wi;
    cmul(ar[1], ai[1], pr, pi);
    #pragma unroll
    for (int k = 2; k < 8; ++k) {
        float nr = pr*wr - pi*wi;
        pi = pr*wi + pi*wr;
        pr = nr;
        cmul(ar[k], ai[k], pr, pi);
    }
}

// TWO interleaved 512-pt FFTs (A,B) through ONE per-wave scratch (544+544).
// In:  ar[j] = x[64*j + lane];  Out: ar[d] = X[(lane>>3) + 8*(lane&7) + 64*d]
__device__ __forceinline__ void fft512x2(float Ar[8], float Ai[8],
                                         float Br[8], float Bi[8],
                                         float* Lr, float* Li, int lane) {
    float s1, c1, s2, c2;
    int k1 = lane >> 3, b = lane & 7;
    __sincosf((float)lane * (-6.28318530717958647692f/512.0f), &s1, &c1);
    __sincosf((float)b    * (-6.28318530717958647692f/64.0f),  &s2, &c2);
    dft8(Ar, Ai); twiddle7(Ar, Ai, c1, s1);
    dft8(Br, Bi); twiddle7(Br, Bi, c1, s1);
    #pragma unroll
    for (int j = 0; j < 8; ++j) { Lr[j*68+lane] = Ar[j]; Li[j*68+lane] = Ai[j]; }
    #pragma unroll
    for (int a = 0; a < 8; ++a) { Ar[a] = Lr[k1*68+8*a+b]; Ai[a] = Li[k1*68+8*a+b]; }
    #pragma unroll
    for (int j = 0; j < 8; ++j) { Lr[j*68+lane] = Br[j]; Li[j*68+lane] = Bi[j]; }
    dft8(Ar, Ai); twiddle7(Ar, Ai, c2, s2);
    #pragma unroll
    for (int a = 0; a < 8; ++a) { Br[a] = Lr[k1*68+8*a+b]; Bi[a] = Li[k1*68+8*a+b]; }
    dft8(Br, Bi); twiddle7(Br, Bi, c2, s2);
    #pragma unroll
    for (int cc = 0; cc < 8; ++cc) {
        int ad = k1*68 + 8*cc + ((b + cc) & 7);
        Lr[ad] = Ar[cc]; Li[ad] = Ai[cc];
    }
    #pragma unroll
    for (int bb = 0; bb < 8; ++bb) {
        int ad = k1*68 + 8*b + ((bb + b) & 7);
        Ar[bb] = Lr[ad]; Ai[bb] = Li[ad];
    }
    #pragma unroll
    for (int cc = 0; cc < 8; ++cc) {
        int ad = k1*68 + 8*cc + ((b + cc) & 7);
        Lr[ad] = Br[cc]; Li[ad] = Bi[cc];
    }
    dft8(Ar, Ai);
    #pragma unroll
    for (int bb = 0; bb < 8; ++bb) {
        int ad = k1*68 + 8*b + ((bb + b) & 7);
        Br[bb] = Lr[ad]; Bi[bb] = Li[ad];
    }
    dft8(Br, Bi);
}

// Row stage: pack pred-row (re) + tgt-row (im) into one complex FFT; rows A,B
// interleaved; unpack Hermitian halves; store cols 0..256 in the
// cg-interleaved layout [img][cg][row][4] with fully coalesced float4 stores.
// Block = 4 waves x 2 rows = 8 rows. 24*64 blocks.
__global__ __launch_bounds__(256, 4) void k_rowfft(const float* __restrict__ pred,
                                                   const float* __restrict__ tgt,
                                                   float* __restrict__ ws) {
    __shared__ float smem[4352];           // 4x1088 scratch; tiles [8][260]x2 alias
    int t = threadIdx.x, lane = t & 63, w = t >> 6;
    int b = blockIdx.x;
    int img = b >> 6;
    int r0 = (b & 63) << 3;
    int rA = r0 + 2*w;
    const float* pA = pred + (size_t)img*PLANE + (size_t)rA*HW;
    const float* tA = tgt  + (size_t)img*PLANE + (size_t)rA*HW;
    float arA[8], aiA[8], arB[8], aiB[8];
    #pragma unroll
    for (int j = 0; j < 8; ++j) {          // all 32 loads in flight
        arA[j] = pA[64*j + lane];      aiA[j] = tA[64*j + lane];
        arB[j] = pA[HW + 64*j + lane]; aiB[j] = tA[HW + 64*j + lane];
    }
    float* Lr = smem + w*1088;
    float* Li = Lr + 544;
    fft512x2(arA, aiA, arB, aiB, Lr, Li, lane);
    float PrA[4], PiA[4], TrA[4], TiA[4], P256A=0.f, T256A=0.f;
    float PrB[4], PiB[4], TrB[4], TiB[4], P256B=0.f, T256B=0.f;
    #pragma unroll
    for (int d = 0; d < 8; ++d) {
        int k = (lane>>3) + ((lane&7)<<3) + (d<<6);
        Lr[k] = arA[d]; Li[k] = aiA[d];
    }
    #pragma unroll
    for (int m = 0; m < 4; ++m) {
        int kk = 64*m + lane, j2 = (512 - kk) & 511;
        float z1r = Lr[kk], z1i = Li[kk], z2r = Lr[j2], z2i = Li[j2];
        PrA[m] = 0.5f*(z1r+z2r); PiA[m] = 0.5f*(z1i-z2i);
        TrA[m] = 0.5f*(z1i+z2i); TiA[m] = 0.5f*(z2r-z1r);
    }
    if (lane == 0) { P256A = Lr[256]; T256A = Li[256]; }
    #pragma unroll
    for (int d = 0; d < 8; ++d) {
        int k = (lane>>3) + ((lane&7)<<3) + (d<<6);
        Lr[k] = arB[d]; Li[k] = aiB[d];
    }
    #pragma unroll
    for (int m = 0; m < 4; ++m) {
        int kk = 64*m + lane, j2 = (512 - kk) & 511;
        float z1r = Lr[kk], z1i = Li[kk], z2r = Lr[j2], z2i = Li[j2];
        PrB[m] = 0.5f*(z1r+z2r); PiB[m] = 0.5f*(z1i-z2i);
        TrB[m] = 0.5f*(z1i+z2i); TiB[m] = 0.5f*(z2r-z1r);
    }
    if (lane == 0) { P256B = Lr[256]; T256B = Li[256]; }

    float* tR = smem;                      // [8][260]
    float* tI = smem + 2080;
    // ---- P pass ----
    __syncthreads();
    #pragma unroll
    for (int m = 0; m < 4; ++m) {
        int kk = 64*m + lane;
        tR[(2*w)*260 + kk]   = PrA[m]; tR[(2*w+1)*260 + kk] = PrB[m];
        tI[(2*w)*260 + kk]   = PiA[m]; tI[(2*w+1)*260 + kk] = PiB[m];
    }
    if (lane == 0) {
        tR[(2*w)*260 + 256] = P256A; tR[(2*w+1)*260 + 256] = P256B;
        tI[(2*w)*260 + 256] = 0.f;   tI[(2*w+1)*260 + 256] = 0.f;
    }
    __syncthreads();
    for (int idx = t; idx < 1040; idx += 256) {
        int comp = idx >= 520;
        int q = idx - (comp ? 520 : 0);
        int cg = q >> 3, rl = q & 7;
        const float* Tt = comp ? tI : tR;
        float4 v = *(const float4*)(Tt + rl*260 + 4*cg);
        float* outP = ws + (size_t)(comp ? OFF_PIm : OFF_PR)
                      + (size_t)img*CP2 + cg*2048 + (r0 + rl)*4;
        *(float4*)outP = v;
    }
    // ---- T pass ----
    __syncthreads();
    #pragma unroll
    for (int m = 0; m < 4; ++m) {
        int kk = 64*m + lane;
        tR[(2*w)*260 + kk]   = TrA[m]; tR[(2*w+1)*260 + kk] = TrB[m];
        tI[(2*w)*260 + kk]   = TiA[m]; tI[(2*w+1)*260 + kk] = TiB[m];
    }
    if (lane == 0) {
        tR[(2*w)*260 + 256] = T256A; tR[(2*w+1)*260 + 256] = T256B;
        tI[(2*w)*260 + 256] = 0.f;   tI[(2*w+1)*260 + 256] = 0.f;
    }
    __syncthreads();
    for (int idx = t; idx < 1040; idx += 256) {
        int comp = idx >= 520;
        int q = idx - (comp ? 520 : 0);
        int cg = q >> 3, rl = q & 7;
        const float* Tt = comp ? tI : tR;
        float4 v = *(const float4*)(Tt + rl*260 + 4*cg);
        float* outP = ws + (size_t)(comp ? OFF_TI : OFF_TR)
                      + (size_t)img*CP2 + cg*2048 + (r0 + rl)*4;
        *(float4*)outP = v;
    }
}

// Col stage: interleaved P,T column FFTs from the cg-interleaved layout
// (stride-16B lane loads; 4 sibling waves share the lines via L1);
// per-pixel (mag,d2) stash; pair-binning for the column and its x-mirror.
__global__ __launch_bounds__(256, 4) void k_colfft(const float* __restrict__ ws,
                                                   float* __restrict__ gPM,
                                                   float* __restrict__ gPD) {
    __shared__ float smem[4352];
    __shared__ float binM[NB], binD[NB];
    int t = threadIdx.x, lane = t & 63, w = t >> 6;
    for (int j = t; j < NB; j += 256) { binM[j] = 0.f; binD[j] = 0.f; }
    __syncthreads();
    int b = blockIdx.x;
    int img = b / NG;
    int g = b - img*NG;
    int c = 4*g + w;
    if (c < NC) {
        float* Lr = smem + w*1088;
        float* Li = Lr + 544;
        float prm[8], pim[8], trm[8], tim[8];
        size_t cbase = (size_t)img*CP2 + (size_t)(c >> 2)*2048 + (c & 3);
        const float* cPR = ws + OFF_PR  + cbase;
        const float* cPI = ws + OFF_PIm + cbase;
        const float* cTR = ws + OFF_TR  + cbase;
        const float* cTI = ws + OFF_TI  + cbase;
        #pragma unroll
        for (int j = 0; j < 8; ++j) {      // all 32 loads in flight
            int o = (64*j + lane) << 2;
            prm[j] = cPR[o]; pim[j] = cPI[o];
            trm[j] = cTR[o]; tim[j] = cTI[o];
        }
        fft512x2(prm, pim, trm, tim, Lr, Li, lane);
        #pragma unroll
        for (int d = 0; d < 8; ++d) {
            int ky = (lane>>3) + ((lane&7)<<3) + (d<<6);
            float sp  = prm[d]*prm[d] + pim[d]*pim[d];
            float st_ = trm[d]*trm[d] + tim[d]*tim[d];
            float diff = sp - st_;
            float er = prm[d] + 1e-8f;
            Lr[ky] = 10.0f * __logf(er*er + pim[d]*pim[d]);
            Li[ky] = diff*diff;
        }
        float v1 = (c == 256) ? 511.0f : (float)(2*c + 1);
        bool mir = (c >= 1 && c <= 255);
        float v2 = (float)(2*c - 1);
        #pragma unroll
        for (int p = 0; p < 4; ++p) {
            int ky = lane + 64*p;          // [0,256): pair partner is 511-ky
            float u = (float)(2*ky + 1);
            float sM = Lr[ky] + Lr[511 - ky];
            float sD = Li[ky] + Li[511 - ky];
            int k1 = rbin_odd(u, v1);
            atomicAdd(&binM[k1], sM);
            atomicAdd(&binD[k1], sD);
            if (mir) {
                float s2M = Lr[(512 - ky) & 511] + Lr[ky + 1];
                float s2D = Li[(512 - ky) & 511] + Li[ky + 1];
                int k2 = rbin_odd(u, v2);
                atomicAdd(&binM[k2], s2M);
                atomicAdd(&binD[k2], s2D);
            }
        }
    }
    __syncthreads();
    for (int j = t; j < NB; j += 256) {
        gPM[(size_t)b*NB + j] = binM[j];
        gPD[(size_t)b*NB + j] = binD[j];
    }
}

// Per-image: bin counts via quadrant symmetry (counts[k] = 4x quad count),
// reduce partials -> bin means -> NaN-propagating min/max -> weights ->
// weighted sum -> atomic into d_out. (Weight numerics validated R1-R7.)
__global__ __launch_bounds__(512) void k_final(const float* __restrict__ gPM,
                                               const float* __restrict__ gPD,
                                               float* __restrict__ out) {
    __shared__ int cnt[NB];
    __shared__ float meanb[NB];
    __shared__ float dsum[NB];
    __shared__ float rmin[512], rmax[512];
    __shared__ double sred[512];
    int t = threadIdx.x, img = blockIdx.x;
    for (int j = t; j < NB; j += 512) cnt[j] = 0;
    __syncthreads();
    for (int q = t; q < 65536; q += 512) {
        float u = (float)(2*(q >> 8) + 1);
        float v = (float)(2*(q & 255) + 1);
        atomicAdd(&cnt[rbin_odd(u, v)], 4);
    }
    __syncthreads();
    for (int j = t; j < NB; j += 512) {
        float sm = 0.f, sd = 0.f;
        for (int g = 0; g < NG; ++g) {
            sm += gPM[(size_t)(img*NG + g)*NB + j];
            sd += gPD[(size_t)(img*NG + g)*NB + j];
        }
        meanb[j] = sm / (float)cnt[j];
        dsum[j] = sd;
    }
    __syncthreads();
    float vmin = INFINITY, vmax = -INFINITY;
    if (t >= 1 && t <= 360) { vmin = meanb[t]; vmax = meanb[t]; }
    rmin[t] = vmin; rmax[t] = vmax;
    __syncthreads();
    for (int s = 256; s > 0; s >>= 1) {
        if (t < s) {
            float a = rmin[t], bb = rmin[t+s];
            rmin[t] = (a != a || bb != bb) ? __int_as_float(0x7fc00000) : fminf(a, bb);
            a = rmax[t]; bb = rmax[t+s];
            rmax[t] = (a != a || bb != bb) ? __int_as_float(0x7fc00000) : fmaxf(a, bb);
        }
        __syncthreads();
    }
    float pmin = rmin[0], pmax = rmax[0];
    double part = 0.0;
    for (int k = t; k < NB; k += 512) {
        float wgt;
        if (k == NB - 1) {
            wgt = 1.0f;
        } else {
            int idx = (k == 0) ? 1 : k;
            float e = (meanb[idx] - pmin) / (pmax - pmin);
            float wv = 1.0f - e;
            if (wv != wv) wv = 0.0f;
            wv = fminf(fmaxf(wv, 0.0f), 1.0f);
            wgt = wv;
        }
        part += (double)wgt * (double)dsum[k];
    }
    sred[t] = part;
    __syncthreads();
    for (int s = 256; s > 0; s >>= 1) {
        if (t < s) sred[t] += sred[t+s];
        __syncthreads();
    }
    if (t == 0) atomicAdd(out, (float)(sred[0] / 6291456.0));
}

extern "C" void kernel_launch(void* const* d_in, const int* in_sizes, int n_in,
                              void* d_out, int out_size, void* d_ws, size_t ws_size,
                              hipStream_t stream) {
    const float* pred = (const float*)d_in[0];
    const float* tgt  = (const float*)d_in[1];
    float* ws = (float*)d_ws;
    hipMemsetAsync(d_out, 0, sizeof(float), stream);
    k_rowfft<<<NIMG*64, 256, 0, stream>>>(pred, tgt, ws);
    k_colfft<<<NPB, 256, 0, stream>>>(ws, ws + OFF_PM, ws + OFF_PD);
    k_final<<<NIMG, 512, 0, stream>>>(ws + OFF_PM, ws + OFF_PD, (float*)d_out);
}

// Round 13
// 166.624 us; speedup vs baseline: 1.1193x; 1.0088x over previous
//
#include <hip/hip_runtime.h>
#include <math.h>

#define HW 512
#define NIMG 24              // 8*3 images per tensor
#define NB 362               // radial bins
#define PLANE (HW*HW)
#define NC 257               // spectral columns kept (0..256), Hermitian half
#define NG 65                // col-groups per image (4 cols each; cg64 ragged)
#define NPB (NIMG*NG)        // 1560 partial-bin blocks
#define CP2 133120           // floats per component per image: 65 cg * 512 * 4

// ws layout (float units):
#define OFF_PM  0                          // [NPB*NB] partial mag sums
#define OFF_PD  (NPB*NB)                   // [NPB*NB] partial d sums
#define OFF_PR  (2*NPB*NB)                 // P real, [img][cg][row][4]
#define OFF_PIm (OFF_PR + NIMG*CP2)        // P imag
#define OFF_TR  (OFF_PR + 2*NIMG*CP2)      // T real
#define OFF_TI  (OFF_PR + 3*NIMG*CP2)      // T imag
#define OFF_RM  (OFF_PR + 4*NIMG*CP2)      // [NIMG*NB] reduced mag sums
#define OFF_RD  (OFF_RM + NIMG*NB)         // [NIMG*NB] reduced d sums
// total ~55.7 MiB

// Exact bin for ODD integer u,v (as floats): m2 = u^2+v^2 == 2 mod 8 is never
// a perfect even square, boundary gap >= 1/(4k) ~ 6.9e-4 >> 1ulp sqrt err.
__device__ __forceinline__ int rbin_odd(float u, float v) {
    return (int)(sqrtf(fmaf(u, u, v*v)) * 0.5f);
}

__device__ __forceinline__ void cmul(float& xr, float& xi, float wr, float wi) {
    float r = xr*wr - xi*wi;
    xi = xr*wi + xi*wr;
    xr = r;
}

// 8-point DFT in registers, natural order (validated R2-R10).
__device__ __forceinline__ void dft8(float ar[8], float ai[8]) {
    const float C = 0.70710678118654752440f;
    float t0r=ar[0]+ar[4], t0i=ai[0]+ai[4];
    float t1r=ar[0]-ar[4], t1i=ai[0]-ai[4];
    float t2r=ar[2]+ar[6], t2i=ai[2]+ai[6];
    float t3r=ar[2]-ar[6], t3i=ai[2]-ai[6];
    float E0r=t0r+t2r, E0i=t0i+t2i;
    float E2r=t0r-t2r, E2i=t0i-t2i;
    float E1r=t1r+t3i, E1i=t1i-t3r;
    float E3r=t1r-t3i, E3i=t1i+t3r;
    float u0r=ar[1]+ar[5], u0i=ai[1]+ai[5];
    float u1r=ar[1]-ar[5], u1i=ai[1]-ai[5];
    float u2r=ar[3]+ar[7], u2i=ai[3]+ai[7];
    float u3r=ar[3]-ar[7], u3i=ai[3]-ai[7];
    float O0r=u0r+u2r, O0i=u0i+u2i;
    float O2r=u0r-u2r, O2i=u0i-u2i;
    float O1r=u1r+u3i, O1i=u1i-u3r;
    float O3r=u1r-u3i, O3i=u1i+u3r;
    float W1r = C*(O1r+O1i), W1i = C*(O1i-O1r);
    float W2r = O2i,         W2i = -O2r;
    float W3r = C*(O3i-O3r), W3i = -C*(O3r+O3i);
    ar[0]=E0r+O0r; ai[0]=E0i+O0i;
    ar[4]=E0r-O0r; ai[4]=E0i-O0i;
    ar[1]=E1r+W1r; ai[1]=E1i+W1i;
    ar[5]=E1r-W1r; ai[5]=E1i-W1i;
    ar[2]=E2r+W2r; ai[2]=E2i+W2i;
    ar[6]=E2r-W2r; ai[6]=E2i-W2i;
    ar[3]=E3r+W3r; ai[3]=E3i+W3i;
    ar[7]=E3r-W3r; ai[7]=E3i-W3i;
}

__device__ __forceinline__ void twiddle7(float ar[8], float ai[8], float wr, float wi) {
    float pr = wr, pi = wi;
    cmul(ar[1], ai[1], pr, pi);
    #pragma unroll
    for (int k = 2; k < 8; ++k) {
        float nr = pr*wr - pi*wi;
        pi = pr*wi + pi*wr;
        pr = nr;
        cmul(ar[k], ai[k], pr, pi);
    }
}

// TWO interleaved 512-pt FFTs through one per-wave scratch (validated R7-R10).
__device__ __forceinline__ void fft512x2(float Ar[8], float Ai[8],
                                         float Br[8], float Bi[8],
                                         float* Lr, float* Li, int lane) {
    float s1, c1, s2, c2;
    int k1 = lane >> 3, b = lane & 7;
    __sincosf((float)lane * (-6.28318530717958647692f/512.0f), &s1, &c1);
    __sincosf((float)b    * (-6.28318530717958647692f/64.0f),  &s2, &c2);
    dft8(Ar, Ai); twiddle7(Ar, Ai, c1, s1);
    dft8(Br, Bi); twiddle7(Br, Bi, c1, s1);
    #pragma unroll
    for (int j = 0; j < 8; ++j) { Lr[j*68+lane] = Ar[j]; Li[j*68+lane] = Ai[j]; }
    #pragma unroll
    for (int a = 0; a < 8; ++a) { Ar[a] = Lr[k1*68+8*a+b]; Ai[a] = Li[k1*68+8*a+b]; }
    #pragma unroll
    for (int j = 0; j < 8; ++j) { Lr[j*68+lane] = Br[j]; Li[j*68+lane] = Bi[j]; }
    dft8(Ar, Ai); twiddle7(Ar, Ai, c2, s2);
    #pragma unroll
    for (int a = 0; a < 8; ++a) { Br[a] = Lr[k1*68+8*a+b]; Bi[a] = Li[k1*68+8*a+b]; }
    dft8(Br, Bi); twiddle7(Br, Bi, c2, s2);
    #pragma unroll
    for (int cc = 0; cc < 8; ++cc) {
        int ad = k1*68 + 8*cc + ((b + cc) & 7);
        Lr[ad] = Ar[cc]; Li[ad] = Ai[cc];
    }
    #pragma unroll
    for (int bb = 0; bb < 8; ++bb) {
        int ad = k1*68 + 8*b + ((bb + b) & 7);
        Ar[bb] = Lr[ad]; Ai[bb] = Li[ad];
    }
    #pragma unroll
    for (int cc = 0; cc < 8; ++cc) {
        int ad = k1*68 + 8*cc + ((b + cc) & 7);
        Lr[ad] = Br[cc]; Li[ad] = Bi[cc];
    }
    dft8(Ar, Ai);
    #pragma unroll
    for (int bb = 0; bb < 8; ++bb) {
        int ad = k1*68 + 8*b + ((bb + b) & 7);
        Br[bb] = Lr[ad]; Bi[bb] = Li[ad];
    }
    dft8(Br, Bi);
}

// Row stage (R10-proven): pack pred+tgt rows into one complex FFT,
// 2 rows per wave, Hermitian unpack, coalesced cg-layout stores.
__global__ __launch_bounds__(256, 4) void k_rowfft(const float* __restrict__ pred,
                                                   const float* __restrict__ tgt,
                                                   float* __restrict__ ws) {
    __shared__ float smem[4352];
    int t = threadIdx.x, lane = t & 63, w = t >> 6;
    int b = blockIdx.x;
    int img = b >> 6;
    int r0 = (b & 63) << 3;
    int rA = r0 + 2*w;
    const float* pA = pred + (size_t)img*PLANE + (size_t)rA*HW;
    const float* tA = tgt  + (size_t)img*PLANE + (size_t)rA*HW;
    float arA[8], aiA[8], arB[8], aiB[8];
    #pragma unroll
    for (int j = 0; j < 8; ++j) {
        arA[j] = pA[64*j + lane];      aiA[j] = tA[64*j + lane];
        arB[j] = pA[HW + 64*j + lane]; aiB[j] = tA[HW + 64*j + lane];
    }
    float* Lr = smem + w*1088;
    float* Li = Lr + 544;
    fft512x2(arA, aiA, arB, aiB, Lr, Li, lane);
    float PrA[4], PiA[4], TrA[4], TiA[4], P256A=0.f, T256A=0.f;
    float PrB[4], PiB[4], TrB[4], TiB[4], P256B=0.f, T256B=0.f;
    #pragma unroll
    for (int d = 0; d < 8; ++d) {
        int k = (lane>>3) + ((lane&7)<<3) + (d<<6);
        Lr[k] = arA[d]; Li[k] = aiA[d];
    }
    #pragma unroll
    for (int m = 0; m < 4; ++m) {
        int kk = 64*m + lane, j2 = (512 - kk) & 511;
        float z1r = Lr[kk], z1i = Li[kk], z2r = Lr[j2], z2i = Li[j2];
        PrA[m] = 0.5f*(z1r+z2r); PiA[m] = 0.5f*(z1i-z2i);
        TrA[m] = 0.5f*(z1i+z2i); TiA[m] = 0.5f*(z2r-z1r);
    }
    if (lane == 0) { P256A = Lr[256]; T256A = Li[256]; }
    #pragma unroll
    for (int d = 0; d < 8; ++d) {
        int k = (lane>>3) + ((lane&7)<<3) + (d<<6);
        Lr[k] = arB[d]; Li[k] = aiB[d];
    }
    #pragma unroll
    for (int m = 0; m < 4; ++m) {
        int kk = 64*m + lane, j2 = (512 - kk) & 511;
        float z1r = Lr[kk], z1i = Li[kk], z2r = Lr[j2], z2i = Li[j2];
        PrB[m] = 0.5f*(z1r+z2r); PiB[m] = 0.5f*(z1i-z2i);
        TrB[m] = 0.5f*(z1i+z2i); TiB[m] = 0.5f*(z2r-z1r);
    }
    if (lane == 0) { P256B = Lr[256]; T256B = Li[256]; }

    float* tR = smem;                      // [8][260]
    float* tI = smem + 2080;
    __syncthreads();
    #pragma unroll
    for (int m = 0; m < 4; ++m) {
        int kk = 64*m + lane;
        tR[(2*w)*260 + kk]   = PrA[m]; tR[(2*w+1)*260 + kk] = PrB[m];
        tI[(2*w)*260 + kk]   = PiA[m]; tI[(2*w+1)*260 + kk] = PiB[m];
    }
    if (lane == 0) {
        tR[(2*w)*260 + 256] = P256A; tR[(2*w+1)*260 + 256] = P256B;
        tI[(2*w)*260 + 256] = 0.f;   tI[(2*w+1)*260 + 256] = 0.f;
    }
    __syncthreads();
    for (int idx = t; idx < 1040; idx += 256) {
        int comp = idx >= 520;
        int q = idx - (comp ? 520 : 0);
        int cg = q >> 3, rl = q & 7;
        const float* Tt = comp ? tI : tR;
        float4 v = *(const float4*)(Tt + rl*260 + 4*cg);
        float* outP = ws + (size_t)(comp ? OFF_PIm : OFF_PR)
                      + (size_t)img*CP2 + cg*2048 + (r0 + rl)*4;
        *(float4*)outP = v;
    }
    __syncthreads();
    #pragma unroll
    for (int m = 0; m < 4; ++m) {
        int kk = 64*m + lane;
        tR[(2*w)*260 + kk]   = TrA[m]; tR[(2*w+1)*260 + kk] = TrB[m];
        tI[(2*w)*260 + kk]   = TiA[m]; tI[(2*w+1)*260 + kk] = TiB[m];
    }
    if (lane == 0) {
        tR[(2*w)*260 + 256] = T256A; tR[(2*w+1)*260 + 256] = T256B;
        tI[(2*w)*260 + 256] = 0.f;   tI[(2*w+1)*260 + 256] = 0.f;
    }
    __syncthreads();
    for (int idx = t; idx < 1040; idx += 256) {
        int comp = idx >= 520;
        int q = idx - (comp ? 520 : 0);
        int cg = q >> 3, rl = q & 7;
        const float* Tt = comp ? tI : tR;
        float4 v = *(const float4*)(Tt + rl*260 + 4*cg);
        float* outP = ws + (size_t)(comp ? OFF_TI : OFF_TR)
                      + (size_t)img*CP2 + cg*2048 + (r0 + rl)*4;
        *(float4*)outP = v;
    }
}

// Col stage (R10-proven): interleaved P,T column FFTs from the cg layout;
// per-pixel (mag,d2) stash; pair-binning for the column and its x-mirror.
__global__ __launch_bounds__(256, 4) void k_colfft(const float* __restrict__ ws,
                                                   float* __restrict__ gPM,
                                                   float* __restrict__ gPD) {
    __shared__ float smem[4352];
    __shared__ float binM[NB], binD[NB];
    int t = threadIdx.x, lane = t & 63, w = t >> 6;
    for (int j = t; j < NB; j += 256) { binM[j] = 0.f; binD[j] = 0.f; }
    __syncthreads();
    int b = blockIdx.x;
    int img = b / NG;
    int g = b - img*NG;
    int c = 4*g + w;
    if (c < NC) {
        float* Lr = smem + w*1088;
        float* Li = Lr + 544;
        float prm[8], pim[8], trm[8], tim[8];
        size_t cbase = (size_t)img*CP2 + (size_t)(c >> 2)*2048 + (c & 3);
        const float* cPR = ws + OFF_PR  + cbase;
        const float* cPI = ws + OFF_PIm + cbase;
        const float* cTR = ws + OFF_TR  + cbase;
        const float* cTI = ws + OFF_TI  + cbase;
        #pragma unroll
        for (int j = 0; j < 8; ++j) {      // all 32 loads in flight
            int o = (64*j + lane) << 2;
            prm[j] = cPR[o]; pim[j] = cPI[o];
            trm[j] = cTR[o]; tim[j] = cTI[o];
        }
        fft512x2(prm, pim, trm, tim, Lr, Li, lane);
        #pragma unroll
        for (int d = 0; d < 8; ++d) {
            int ky = (lane>>3) + ((lane&7)<<3) + (d<<6);
            float sp  = prm[d]*prm[d] + pim[d]*pim[d];
            float st_ = trm[d]*trm[d] + tim[d]*tim[d];
            float diff = sp - st_;
            float er = prm[d] + 1e-8f;
            Lr[ky] = 10.0f * __logf(er*er + pim[d]*pim[d]);
            Li[ky] = diff*diff;
        }
        float v1 = (c == 256) ? 511.0f : (float)(2*c + 1);
        bool mir = (c >= 1 && c <= 255);
        float v2 = (float)(2*c - 1);
        #pragma unroll
        for (int p = 0; p < 4; ++p) {
            int ky = lane + 64*p;          // [0,256): pair partner is 511-ky
            float u = (float)(2*ky + 1);
            float sM = Lr[ky] + Lr[511 - ky];
            float sD = Li[ky] + Li[511 - ky];
            int k1 = rbin_odd(u, v1);
            atomicAdd(&binM[k1], sM);
            atomicAdd(&binD[k1], sD);
            if (mir) {
                float s2M = Lr[(512 - ky) & 511] + Lr[ky + 1];
                float s2D = Li[(512 - ky) & 511] + Li[ky + 1];
                int k2 = rbin_odd(u, v2);
                atomicAdd(&binM[k2], s2M);
                atomicAdd(&binD[k2], s2D);
            }
        }
    }
    __syncthreads();
    for (int j = t; j < NB; j += 256) {
        gPM[(size_t)b*NB + j] = binM[j];
        gPD[(size_t)b*NB + j] = binD[j];
    }
}

// Partial-bin reduction: 24 images x 12 bin-chunks; 32 bins x 8 group-slices.
__global__ __launch_bounds__(256) void k_reduce(const float* __restrict__ gPM,
                                                const float* __restrict__ gPD,
                                                float* __restrict__ rM,
                                                float* __restrict__ rD) {
    __shared__ float sm[8][33], sd2[8][33];
    int b = blockIdx.x;
    int img = b / 12, ch = b - img*12;
    int jl = threadIdx.x & 31, gs = threadIdx.x >> 5;
    int j = ch*32 + jl;
    float aM = 0.f, aD = 0.f;
    if (j < NB) {
        for (int g = gs; g < NG; g += 8) {
            aM += gPM[(size_t)(img*NG + g)*NB + j];
            aD += gPD[(size_t)(img*NG + g)*NB + j];
        }
    }
    sm[gs][jl] = aM; sd2[gs][jl] = aD;
    __syncthreads();
    if (threadIdx.x < 32 && j < NB) {
        float tM = 0.f, tD = 0.f;
        #pragma unroll
        for (int s = 0; s < 8; ++s) { tM += sm[s][jl]; tD += sd2[s][jl]; }
        rM[img*NB + j] = tM;
        rD[img*NB + j] = tD;
    }
}

// Per-image final: quadrant-symmetry bin counts, means, NaN-propagating
// min/max, weights, weighted sum -> atomic into d_out (numerics R1-R10).
__global__ __launch_bounds__(512) void k_final(const float* __restrict__ rM,
                                               const float* __restrict__ rD,
                                               float* __restrict__ out) {
    __shared__ int cnt[NB];
    __shared__ float meanb[NB];
    __shared__ float dsum[NB];
    __shared__ float rmin[512], rmax[512];
    __shared__ double sred[512];
    int t = threadIdx.x, img = blockIdx.x;
    for (int j = t; j < NB; j += 512) cnt[j] = 0;
    __syncthreads();
    for (int q = t; q < 65536; q += 512) {
        float u = (float)(2*(q >> 8) + 1);
        float v = (float)(2*(q & 255) + 1);
        atomicAdd(&cnt[rbin_odd(u, v)], 4);
    }
    __syncthreads();
    for (int j = t; j < NB; j += 512) {
        meanb[j] = rM[img*NB + j] / (float)cnt[j];
        dsum[j]  = rD[img*NB + j];
    }
    __syncthreads();
    float vmin = INFINITY, vmax = -INFINITY;
    if (t >= 1 && t <= 360) { vmin = meanb[t]; vmax = meanb[t]; }
    rmin[t] = vmin; rmax[t] = vmax;
    __syncthreads();
    for (int s = 256; s > 0; s >>= 1) {
        if (t < s) {
            float a = rmin[t], bb = rmin[t+s];
            rmin[t] = (a != a || bb != bb) ? __int_as_float(0x7fc00000) : fminf(a, bb);
            a = rmax[t]; bb = rmax[t+s];
            rmax[t] = (a != a || bb != bb) ? __int_as_float(0x7fc00000) : fmaxf(a, bb);
        }
        __syncthreads();
    }
    float pmin = rmin[0], pmax = rmax[0];
    double part = 0.0;
    for (int k = t; k < NB; k += 512) {
        float wgt;
        if (k == NB - 1) {
            wgt = 1.0f;
        } else {
            int idx = (k == 0) ? 1 : k;
            float e = (meanb[idx] - pmin) / (pmax - pmin);
            float wv = 1.0f - e;
            if (wv != wv) wv = 0.0f;
            wv = fminf(fmaxf(wv, 0.0f), 1.0f);
            wgt = wv;
        }
        part += (double)wgt * (double)dsum[k];
    }
    sred[t] = part;
    __syncthreads();
    for (int s = 256; s > 0; s >>= 1) {
        if (t < s) sred[t] += sred[t+s];
        __syncthreads();
    }
    if (t == 0) atomicAdd(out, (float)(sred[0] / 6291456.0));
}

extern "C" void kernel_launch(void* const* d_in, const int* in_sizes, int n_in,
                              void* d_out, int out_size, void* d_ws, size_t ws_size,
                              hipStream_t stream) {
    const float* pred = (const float*)d_in[0];
    const float* tgt  = (const float*)d_in[1];
    float* ws = (float*)d_ws;
    hipMemsetAsync(d_out, 0, sizeof(float), stream);
    k_rowfft<<<NIMG*64, 256, 0, stream>>>(pred, tgt, ws);
    k_colfft<<<NPB, 256, 0, stream>>>(ws, ws + OFF_PM, ws + OFF_PD);
    k_reduce<<<NIMG*12, 256, 0, stream>>>(ws + OFF_PM, ws + OFF_PD,
                                          ws + OFF_RM, ws + OFF_RD);
    k_final<<<NIMG, 512, 0, stream>>>(ws + OFF_RM, ws + OFF_RD, (float*)d_out);
}

// Round 14
// 156.946 us; speedup vs baseline: 1.1883x; 1.0617x over previous
//
#include <hip/hip_runtime.h>
#include <math.h>

#define HW 512
#define NIMG 24              // 8*3 images per tensor
#define NB 362               // radial bins
#define PLANE (HW*HW)
#define NC 257               // spectral columns kept (0..256), Hermitian half
#define NG 65                // col-groups per image (4 cols each; cg64 ragged)
#define NPB (NIMG*NG)        // 1560 partial-bin blocks
#define CP2 133120           // floats per component per image: 65 cg * 512 * 4

// ws layout (float units):
#define OFF_PM  0                          // [NPB*NB] partial mag sums
#define OFF_PD  (NPB*NB)                   // [NPB*NB] partial d sums
#define OFF_PR  (2*NPB*NB)                 // P real, [img][cg][row][4]
#define OFF_PIm (OFF_PR + NIMG*CP2)        // P imag
#define OFF_TR  (OFF_PR + 2*NIMG*CP2)      // T real
#define OFF_TI  (OFF_PR + 3*NIMG*CP2)      // T imag
#define OFF_RM  (OFF_PR + 4*NIMG*CP2)      // [NIMG*NB] reduced mag sums
#define OFF_RD  (OFF_RM + NIMG*NB)         // [NIMG*NB] reduced d sums
// total ~55.7 MiB

// Exact bin for ODD integer u,v (as floats): m2 = u^2+v^2 == 2 mod 8 is never
// a perfect even square, boundary gap >= 1/(4k) ~ 6.9e-4 >> 1ulp sqrt err.
__device__ __forceinline__ int rbin_odd(float u, float v) {
    return (int)(sqrtf(fmaf(u, u, v*v)) * 0.5f);
}

__device__ __forceinline__ void cmul(float& xr, float& xi, float wr, float wi) {
    float r = xr*wr - xi*wi;
    xi = xr*wi + xi*wr;
    xr = r;
}

// 8-point DFT in registers, natural order (validated R2-R13).
__device__ __forceinline__ void dft8(float ar[8], float ai[8]) {
    const float C = 0.70710678118654752440f;
    float t0r=ar[0]+ar[4], t0i=ai[0]+ai[4];
    float t1r=ar[0]-ar[4], t1i=ai[0]-ai[4];
    float t2r=ar[2]+ar[6], t2i=ai[2]+ai[6];
    float t3r=ar[2]-ar[6], t3i=ai[2]-ai[6];
    float E0r=t0r+t2r, E0i=t0i+t2i;
    float E2r=t0r-t2r, E2i=t0i-t2i;
    float E1r=t1r+t3i, E1i=t1i-t3r;
    float E3r=t1r-t3i, E3i=t1i+t3r;
    float u0r=ar[1]+ar[5], u0i=ai[1]+ai[5];
    float u1r=ar[1]-ar[5], u1i=ai[1]-ai[5];
    float u2r=ar[3]+ar[7], u2i=ai[3]+ai[7];
    float u3r=ar[3]-ar[7], u3i=ai[3]-ai[7];
    float O0r=u0r+u2r, O0i=u0i+u2i;
    float O2r=u0r-u2r, O2i=u0i-u2i;
    float O1r=u1r+u3i, O1i=u1i-u3r;
    float O3r=u1r-u3i, O3i=u1i+u3r;
    float W1r = C*(O1r+O1i), W1i = C*(O1i-O1r);
    float W2r = O2i,         W2i = -O2r;
    float W3r = C*(O3i-O3r), W3i = -C*(O3r+O3i);
    ar[0]=E0r+O0r; ai[0]=E0i+O0i;
    ar[4]=E0r-O0r; ai[4]=E0i-O0i;
    ar[1]=E1r+W1r; ai[1]=E1i+W1i;
    ar[5]=E1r-W1r; ai[5]=E1i-W1i;
    ar[2]=E2r+W2r; ai[2]=E2i+W2i;
    ar[6]=E2r-W2r; ai[6]=E2i-W2i;
    ar[3]=E3r+W3r; ai[3]=E3i+W3i;
    ar[7]=E3r-W3r; ai[7]=E3i-W3i;
}

__device__ __forceinline__ void twiddle7(float ar[8], float ai[8], float wr, float wi) {
    float pr = wr, pi = wi;
    cmul(ar[1], ai[1], pr, pi);
    #pragma unroll
    for (int k = 2; k < 8; ++k) {
        float nr = pr*wr - pi*wi;
        pi = pr*wi + pi*wr;
        pr = nr;
        cmul(ar[k], ai[k], pr, pi);
    }
}

// TWO interleaved 512-pt FFTs through one per-wave scratch (validated R7-R13).
__device__ __forceinline__ void fft512x2(float Ar[8], float Ai[8],
                                         float Br[8], float Bi[8],
                                         float* Lr, float* Li, int lane) {
    float s1, c1, s2, c2;
    int k1 = lane >> 3, b = lane & 7;
    __sincosf((float)lane * (-6.28318530717958647692f/512.0f), &s1, &c1);
    __sincosf((float)b    * (-6.28318530717958647692f/64.0f),  &s2, &c2);
    dft8(Ar, Ai); twiddle7(Ar, Ai, c1, s1);
    dft8(Br, Bi); twiddle7(Br, Bi, c1, s1);
    #pragma unroll
    for (int j = 0; j < 8; ++j) { Lr[j*68+lane] = Ar[j]; Li[j*68+lane] = Ai[j]; }
    #pragma unroll
    for (int a = 0; a < 8; ++a) { Ar[a] = Lr[k1*68+8*a+b]; Ai[a] = Li[k1*68+8*a+b]; }
    #pragma unroll
    for (int j = 0; j < 8; ++j) { Lr[j*68+lane] = Br[j]; Li[j*68+lane] = Bi[j]; }
    dft8(Ar, Ai); twiddle7(Ar, Ai, c2, s2);
    #pragma unroll
    for (int a = 0; a < 8; ++a) { Br[a] = Lr[k1*68+8*a+b]; Bi[a] = Li[k1*68+8*a+b]; }
    dft8(Br, Bi); twiddle7(Br, Bi, c2, s2);
    #pragma unroll
    for (int cc = 0; cc < 8; ++cc) {
        int ad = k1*68 + 8*cc + ((b + cc) & 7);
        Lr[ad] = Ar[cc]; Li[ad] = Ai[cc];
    }
    #pragma unroll
    for (int bb = 0; bb < 8; ++bb) {
        int ad = k1*68 + 8*b + ((bb + b) & 7);
        Ar[bb] = Lr[ad]; Ai[bb] = Li[ad];
    }
    #pragma unroll
    for (int cc = 0; cc < 8; ++cc) {
        int ad = k1*68 + 8*cc + ((b + cc) & 7);
        Lr[ad] = Br[cc]; Li[ad] = Bi[cc];
    }
    dft8(Ar, Ai);
    #pragma unroll
    for (int bb = 0; bb < 8; ++bb) {
        int ad = k1*68 + 8*b + ((bb + b) & 7);
        Br[bb] = Lr[ad]; Bi[bb] = Li[ad];
    }
    dft8(Br, Bi);
}

// Row stage (R10/R13-proven, unchanged).
__global__ __launch_bounds__(256, 4) void k_rowfft(const float* __restrict__ pred,
                                                   const float* __restrict__ tgt,
                                                   float* __restrict__ ws) {
    __shared__ float smem[4352];
    int t = threadIdx.x, lane = t & 63, w = t >> 6;
    int b = blockIdx.x;
    int img = b >> 6;
    int r0 = (b & 63) << 3;
    int rA = r0 + 2*w;
    const float* pA = pred + (size_t)img*PLANE + (size_t)rA*HW;
    const float* tA = tgt  + (size_t)img*PLANE + (size_t)rA*HW;
    float arA[8], aiA[8], arB[8], aiB[8];
    #pragma unroll
    for (int j = 0; j < 8; ++j) {
        arA[j] = pA[64*j + lane];      aiA[j] = tA[64*j + lane];
        arB[j] = pA[HW + 64*j + lane]; aiB[j] = tA[HW + 64*j + lane];
    }
    float* Lr = smem + w*1088;
    float* Li = Lr + 544;
    fft512x2(arA, aiA, arB, aiB, Lr, Li, lane);
    float PrA[4], PiA[4], TrA[4], TiA[4], P256A=0.f, T256A=0.f;
    float PrB[4], PiB[4], TrB[4], TiB[4], P256B=0.f, T256B=0.f;
    #pragma unroll
    for (int d = 0; d < 8; ++d) {
        int k = (lane>>3) + ((lane&7)<<3) + (d<<6);
        Lr[k] = arA[d]; Li[k] = aiA[d];
    }
    #pragma unroll
    for (int m = 0; m < 4; ++m) {
        int kk = 64*m + lane, j2 = (512 - kk) & 511;
        float z1r = Lr[kk], z1i = Li[kk], z2r = Lr[j2], z2i = Li[j2];
        PrA[m] = 0.5f*(z1r+z2r); PiA[m] = 0.5f*(z1i-z2i);
        TrA[m] = 0.5f*(z1i+z2i); TiA[m] = 0.5f*(z2r-z1r);
    }
    if (lane == 0) { P256A = Lr[256]; T256A = Li[256]; }
    #pragma unroll
    for (int d = 0; d < 8; ++d) {
        int k = (lane>>3) + ((lane&7)<<3) + (d<<6);
        Lr[k] = arB[d]; Li[k] = aiB[d];
    }
    #pragma unroll
    for (int m = 0; m < 4; ++m) {
        int kk = 64*m + lane, j2 = (512 - kk) & 511;
        float z1r = Lr[kk], z1i = Li[kk], z2r = Lr[j2], z2i = Li[j2];
        PrB[m] = 0.5f*(z1r+z2r); PiB[m] = 0.5f*(z1i-z2i);
        TrB[m] = 0.5f*(z1i+z2i); TiB[m] = 0.5f*(z2r-z1r);
    }
    if (lane == 0) { P256B = Lr[256]; T256B = Li[256]; }

    float* tR = smem;                      // [8][260]
    float* tI = smem + 2080;
    __syncthreads();
    #pragma unroll
    for (int m = 0; m < 4; ++m) {
        int kk = 64*m + lane;
        tR[(2*w)*260 + kk]   = PrA[m]; tR[(2*w+1)*260 + kk] = PrB[m];
        tI[(2*w)*260 + kk]   = PiA[m]; tI[(2*w+1)*260 + kk] = PiB[m];
    }
    if (lane == 0) {
        tR[(2*w)*260 + 256] = P256A; tR[(2*w+1)*260 + 256] = P256B;
        tI[(2*w)*260 + 256] = 0.f;   tI[(2*w+1)*260 + 256] = 0.f;
    }
    __syncthreads();
    for (int idx = t; idx < 1040; idx += 256) {
        int comp = idx >= 520;
        int q = idx - (comp ? 520 : 0);
        int cg = q >> 3, rl = q & 7;
        const float* Tt = comp ? tI : tR;
        float4 v = *(const float4*)(Tt + rl*260 + 4*cg);
        float* outP = ws + (size_t)(comp ? OFF_PIm : OFF_PR)
                      + (size_t)img*CP2 + cg*2048 + (r0 + rl)*4;
        *(float4*)outP = v;
    }
    __syncthreads();
    #pragma unroll
    for (int m = 0; m < 4; ++m) {
        int kk = 64*m + lane;
        tR[(2*w)*260 + kk]   = TrA[m]; tR[(2*w+1)*260 + kk] = TrB[m];
        tI[(2*w)*260 + kk]   = TiA[m]; tI[(2*w+1)*260 + kk] = TiB[m];
    }
    if (lane == 0) {
        tR[(2*w)*260 + 256] = T256A; tR[(2*w+1)*260 + 256] = T256B;
        tI[(2*w)*260 + 256] = 0.f;   tI[(2*w+1)*260 + 256] = 0.f;
    }
    __syncthreads();
    for (int idx = t; idx < 1040; idx += 256) {
        int comp = idx >= 520;
        int q = idx - (comp ? 520 : 0);
        int cg = q >> 3, rl = q & 7;
        const float* Tt = comp ? tI : tR;
        float4 v = *(const float4*)(Tt + rl*260 + 4*cg);
        float* outP = ws + (size_t)(comp ? OFF_TI : OFF_TR)
                      + (size_t)img*CP2 + cg*2048 + (r0 + rl)*4;
        *(float4*)outP = v;
    }
}

// Flush helper: run-collapsed atomic pair.
__device__ __forceinline__ void flush2(float* binM, float* binD, int k,
                                       float aM, float aD) {
    atomicAdd(&binM[k], aM);
    atomicAdd(&binD[k], aD);
}

// Col stage: FFT identical to R13; binning restructured so each lane owns
// 4 CONTIGUOUS pairs -> monotone bins (dk<=1/step) -> register run-collapse,
// ds_read_b128 pair loads, ~2.5 atomics/pass instead of 4 with ~4x less
// same-address lane collision.
__global__ __launch_bounds__(256, 4) void k_colfft(const float* __restrict__ ws,
                                                   float* __restrict__ gPM,
                                                   float* __restrict__ gPD) {
    __shared__ float smem[4352];
    __shared__ float binM[NB], binD[NB];
    int t = threadIdx.x, lane = t & 63, w = t >> 6;
    for (int j = t; j < NB; j += 256) { binM[j] = 0.f; binD[j] = 0.f; }
    __syncthreads();
    int b = blockIdx.x;
    int img = b / NG;
    int g = b - img*NG;
    int c = 4*g + w;
    if (c < NC) {
        float* Lr = smem + w*1088;
        float* Li = Lr + 544;
        float prm[8], pim[8], trm[8], tim[8];
        size_t cbase = (size_t)img*CP2 + (size_t)(c >> 2)*2048 + (c & 3);
        const float* cPR = ws + OFF_PR  + cbase;
        const float* cPI = ws + OFF_PIm + cbase;
        const float* cTR = ws + OFF_TR  + cbase;
        const float* cTI = ws + OFF_TI  + cbase;
        #pragma unroll
        for (int j = 0; j < 8; ++j) {
            int o = (64*j + lane) << 2;
            prm[j] = cPR[o]; pim[j] = cPI[o];
            trm[j] = cTR[o]; tim[j] = cTI[o];
        }
        fft512x2(prm, pim, trm, tim, Lr, Li, lane);
        #pragma unroll
        for (int d = 0; d < 8; ++d) {
            int ky = (lane>>3) + ((lane&7)<<3) + (d<<6);
            float sp  = prm[d]*prm[d] + pim[d]*pim[d];
            float st_ = trm[d]*trm[d] + tim[d]*tim[d];
            float diff = sp - st_;
            float er = prm[d] + 1e-8f;
            Lr[ky] = 10.0f * __logf(er*er + pim[d]*pim[d]);
            Li[ky] = diff*diff;
        }
        __builtin_amdgcn_wave_barrier();
        // ---- contiguous-pair binning: lane owns p = 4*lane .. 4*lane+3 ----
        int p0 = 4*lane;
        float4 fM = *(const float4*)(Lr + p0);        // Lr[p0+j]
        float4 fD = *(const float4*)(Li + p0);
        float4 bM = *(const float4*)(Lr + 508 - p0);  // Lr[508-p0 .. 511-p0]
        float4 bD = *(const float4*)(Li + 508 - p0);
        float eM = Lr[p0 + 4], eD = Li[p0 + 4];       // Lr[p0+4], p0+4 <= 256
        int gidx = (512 - p0) & 511;
        float gM = Lr[gidx], gD = Li[gidx];
        // main pass: s[j] = L[p] + L[511-p]
        float sM[4], sD[4];
        sM[0]=fM.x+bM.w; sM[1]=fM.y+bM.z; sM[2]=fM.z+bM.y; sM[3]=fM.w+bM.x;
        sD[0]=fD.x+bD.w; sD[1]=fD.y+bD.z; sD[2]=fD.z+bD.y; sD[3]=fD.w+bD.x;
        float v1 = (c == 256) ? 511.0f : (float)(2*c + 1);
        {
            int kp = rbin_odd((float)(2*p0 + 1), v1);
            float aM = sM[0], aD = sD[0];
            #pragma unroll
            for (int j = 1; j < 4; ++j) {
                int k = rbin_odd((float)(2*(p0 + j) + 1), v1);
                if (k == kp) { aM += sM[j]; aD += sD[j]; }
                else { flush2(binM, binD, kp, aM, aD); kp = k; aM = sM[j]; aD = sD[j]; }
            }
            flush2(binM, binD, kp, aM, aD);
        }
        if (c >= 1 && c <= 255) {
            // mirror pass: s2[j] = L[(512-p)&511] + L[p+1]
            float s2M[4], s2D[4];
            s2M[0]=gM+fM.y;   s2D[0]=gD+fD.y;
            s2M[1]=bM.w+fM.z; s2D[1]=bD.w+fD.z;
            s2M[2]=bM.z+fM.w; s2D[2]=bD.z+fD.w;
            s2M[3]=bM.y+eM;   s2D[3]=bD.y+eD;
            float v2 = (float)(2*c - 1);
            int kp = rbin_odd((float)(2*p0 + 1), v2);
            float aM = s2M[0], aD = s2D[0];
            #pragma unroll
            for (int j = 1; j < 4; ++j) {
                int k = rbin_odd((float)(2*(p0 + j) + 1), v2);
                if (k == kp) { aM += s2M[j]; aD += s2D[j]; }
                else { flush2(binM, binD, kp, aM, aD); kp = k; aM = s2M[j]; aD = s2D[j]; }
            }
            flush2(binM, binD, kp, aM, aD);
        }
    }
    __syncthreads();
    for (int j = t; j < NB; j += 256) {
        gPM[(size_t)b*NB + j] = binM[j];
        gPD[(size_t)b*NB + j] = binD[j];
    }
}

// Partial-bin reduction (R13-proven, unchanged).
__global__ __launch_bounds__(256) void k_reduce(const float* __restrict__ gPM,
                                                const float* __restrict__ gPD,
                                                float* __restrict__ rM,
                                                float* __restrict__ rD) {
    __shared__ float sm[8][33], sd2[8][33];
    int b = blockIdx.x;
    int img = b / 12, ch = b - img*12;
    int jl = threadIdx.x & 31, gs = threadIdx.x >> 5;
    int j = ch*32 + jl;
    float aM = 0.f, aD = 0.f;
    if (j < NB) {
        for (int g = gs; g < NG; g += 8) {
            aM += gPM[(size_t)(img*NG + g)*NB + j];
            aD += gPD[(size_t)(img*NG + g)*NB + j];
        }
    }
    sm[gs][jl] = aM; sd2[gs][jl] = aD;
    __syncthreads();
    if (threadIdx.x < 32 && j < NB) {
        float tM = 0.f, tD = 0.f;
        #pragma unroll
        for (int s = 0; s < 8; ++s) { tM += sm[s][jl]; tD += sd2[s][jl]; }
        rM[img*NB + j] = tM;
        rD[img*NB + j] = tD;
    }
}

// Per-image final: quadrant counts now with contiguous-v register collapse
// (monotone bins along v for fixed u); rest identical to R13.
__global__ __launch_bounds__(512) void k_final(const float* __restrict__ rM,
                                               const float* __restrict__ rD,
                                               float* __restrict__ out) {
    __shared__ int cnt[NB];
    __shared__ float meanb[NB];
    __shared__ float dsum[NB];
    __shared__ float rmin[512], rmax[512];
    __shared__ double sred[512];
    int t = threadIdx.x, img = blockIdx.x;
    for (int j = t; j < NB; j += 512) cnt[j] = 0;
    __syncthreads();
    {   // thread handles 128 contiguous v for fixed u: q = t*128 + i
        float u = (float)(2*(t >> 1) + 1);
        int vb = (t & 1) << 7;
        int kp = rbin_odd(u, (float)(2*vb + 1));
        int acc = 4;
        for (int i = 1; i < 128; ++i) {
            int k = rbin_odd(u, (float)(2*(vb + i) + 1));
            if (k == kp) acc += 4;
            else { atomicAdd(&cnt[kp], acc); kp = k; acc = 4; }
        }
        atomicAdd(&cnt[kp], acc);
    }
    __syncthreads();
    for (int j = t; j < NB; j += 512) {
        meanb[j] = rM[img*NB + j] / (float)cnt[j];
        dsum[j]  = rD[img*NB + j];
    }
    __syncthreads();
    float vmin = INFINITY, vmax = -INFINITY;
    if (t >= 1 && t <= 360) { vmin = meanb[t]; vmax = meanb[t]; }
    rmin[t] = vmin; rmax[t] = vmax;
    __syncthreads();
    for (int s = 256; s > 0; s >>= 1) {
        if (t < s) {
            float a = rmin[t], bb = rmin[t+s];
            rmin[t] = (a != a || bb != bb) ? __int_as_float(0x7fc00000) : fminf(a, bb);
            a = rmax[t]; bb = rmax[t+s];
            rmax[t] = (a != a || bb != bb) ? __int_as_float(0x7fc00000) : fmaxf(a, bb);
        }
        __syncthreads();
    }
    float pmin = rmin[0], pmax = rmax[0];
    double part = 0.0;
    for (int k = t; k < NB; k += 512) {
        float wgt;
        if (k == NB - 1) {
            wgt = 1.0f;
        } else {
            int idx = (k == 0) ? 1 : k;
            float e = (meanb[idx] - pmin) / (pmax - pmin);
            float wv = 1.0f - e;
            if (wv != wv) wv = 0.0f;
            wv = fminf(fmaxf(wv, 0.0f), 1.0f);
            wgt = wv;
        }
        part += (double)wgt * (double)dsum[k];
    }
    sred[t] = part;
    __syncthreads();
    for (int s = 256; s > 0; s >>= 1) {
        if (t < s) sred[t] += sred[t+s];
        __syncthreads();
    }
    if (t == 0) atomicAdd(out, (float)(sred[0] / 6291456.0));
}

extern "C" void kernel_launch(void* const* d_in, const int* in_sizes, int n_in,
                              void* d_out, int out_size, void* d_ws, size_t ws_size,
                              hipStream_t stream) {
    const float* pred = (const float*)d_in[0];
    const float* tgt  = (const float*)d_in[1];
    float* ws = (float*)d_ws;
    hipMemsetAsync(d_out, 0, sizeof(float), stream);
    k_rowfft<<<NIMG*64, 256, 0, stream>>>(pred, tgt, ws);
    k_colfft<<<NPB, 256, 0, stream>>>(ws, ws + OFF_PM, ws + OFF_PD);
    k_reduce<<<NIMG*12, 256, 0, stream>>>(ws + OFF_PM, ws + OFF_PD,
                                          ws + OFF_RM, ws + OFF_RD);
    k_final<<<NIMG, 512, 0, stream>>>(ws + OFF_RM, ws + OFF_RD, (float*)d_out);
}